// Round 16
// baseline (231.732 us; speedup 1.0000x reference)
//
#include <hip/hip_runtime.h>
#include <hip/hip_bf16.h>
#include <cstdint>
#include <cstddef>

// ---------------------------------------------------------------------------
// E3nnMLPNorm: only the l=1 (d=3) irrep path is nonzero.
// layer0(+colsumsq) -> [gemm(+colsumsq) -> bn+gate] x5 -> final dot
// Precision: bf16 hi+lo pairs, 3 bf16 MFMA per fragment into f32 acc.
// R16: R15's direct-to-register GEMM with a *** 3-deep register pipeline ***.
// R10 vs R15 showed the gemm is latency-bound, not BW-bound: 2-deep reg
// dbuf gives ~466 cy lead time vs ~600-900 cy L3/HBM latency -> per-step
// stall. 3 named fragment sets push lead time to ~700-930 cy.
// 768 one-wave blocks, 64x64 tile/wave, no LDS, no barriers.
// ---------------------------------------------------------------------------

typedef short    s16x8 __attribute__((ext_vector_type(8)));
typedef float    f32x4 __attribute__((ext_vector_type(4)));

#define PLANE 1048576   // 1024*1024 elements per plane

__device__ __forceinline__ unsigned short f2bf(float f) {
  unsigned u = __builtin_bit_cast(unsigned, f);
  u += 0x7FFFu + ((u >> 16) & 1u);              // round-to-nearest-even
  return (unsigned short)(u >> 16);
}
__device__ __forceinline__ float bf2f(unsigned short h) {
  return __builtin_bit_cast(float, (unsigned)h << 16);
}

// byte offset of element (row, k) in the K-blocked bf16 operand layout:
// [row>>6][k>>5][(row>>4)&3][(k>>3)&3][row&15][k&7]
__device__ __forceinline__ size_t ablk(int row, int k) {
  return ((size_t)(row >> 6) << 17) + ((size_t)(k >> 5) << 12)
       + ((size_t)((row >> 4) & 3) << 10) + ((size_t)((k >> 3) & 3) << 8)
       + ((size_t)(row & 15) << 4) + ((size_t)(k & 7) << 1);
}

// ---- W[b,0] (f32 [u][v]) -> blocked bf16 hi/lo (row=v, k=u), 1/32 folded ----
__global__ void convert_w(const float* __restrict__ W,
                          unsigned short* __restrict__ Wh,
                          unsigned short* __restrict__ Wl) {
  __shared__ float t[64][65];
  const int u0 = blockIdx.x * 64, v0 = blockIdx.y * 64;
  const float* Wb = W + (size_t)blockIdx.z * 4194304;   // [5][4][1024][1024], irrep 0
  char* Whb = (char*)(Wh + (size_t)blockIdx.z * PLANE);
  char* Wlb = (char*)(Wl + (size_t)blockIdx.z * PLANE);
  const int c = threadIdx.x & 63, r4 = threadIdx.x >> 6;
#pragma unroll
  for (int i = 0; i < 16; ++i) {
    const int r = i * 4 + r4;
    t[r][c] = Wb[(size_t)(u0 + r) * 1024 + v0 + c];
  }
  __syncthreads();
#pragma unroll
  for (int i = 0; i < 16; ++i) {
    const int r = i * 4 + r4;   // local v index
    const float w = t[c][r] * 0.03125f;      // exact pow2 scale
    const unsigned short hi = f2bf(w);
    const size_t off = ablk(v0 + r, u0 + c);
    *(unsigned short*)(Whb + off) = hi;
    *(unsigned short*)(Wlb + off) = f2bf(w - bf2f(hi));
  }
}

// ---- layer0 + fused colsumsq: pre[i][b][v] (linear f32), var[v] += sum f^2 --
__global__ void layer0_fused(const float* __restrict__ x, const float* __restrict__ w1,
                             float* __restrict__ pre, float* __restrict__ var) {
  const int v = blockIdx.x * 256 + threadIdx.x;
  const int b0 = blockIdx.y * 16;
  const float a0 = w1[v], a1 = w1[1024 + v];
  const float inv = 0.70710678118654752f;
  float ssq = 0.f;
#pragma unroll 4
  for (int bb = 0; bb < 16; ++bb) {
    const int b = b0 + bb;
    const float* xb = x + b * 6;                    // x flat [B][2][3]
#pragma unroll
    for (int i = 0; i < 3; ++i) {
      const float f = (xb[i] * a0 + xb[3 + i] * a1) * inv;
      pre[(size_t)i * PLANE + (size_t)b * 1024 + v] = f;
      ssq += f * f;
    }
  }
  atomicAdd(&var[v], ssq);
}

// ---- batchnorm + norm-gated sigmoid: pre (linear f32) -> blocked bf16 hi/lo -
// block: 16 b x 128 v; thread: b = 16bx + (tid&15), v0 = 128by + (tid>>4)*8.
__global__ void act_kernel(const float* __restrict__ pre, const float* __restrict__ var,
                           const float* __restrict__ bnw,
                           char* __restrict__ ah, char* __restrict__ al) {
  const int tid = threadIdx.x;
  const int b  = blockIdx.x * 16 + (tid & 15);
  const int v0 = blockIdx.y * 128 + (tid >> 4) * 8;
  float s[8];
#pragma unroll
  for (int j = 0; j < 8; ++j)
    s[j] = bnw[v0 + j] / sqrtf(var[v0 + j] * (1.0f / 3072.0f) + 1e-5f);
  float f[3][8];
#pragma unroll
  for (int i = 0; i < 3; ++i) {
    const float4 p0 = *(const float4*)&pre[(size_t)i * PLANE + (size_t)b * 1024 + v0];
    const float4 p1 = *(const float4*)&pre[(size_t)i * PLANE + (size_t)b * 1024 + v0 + 4];
    f[i][0] = p0.x * s[0]; f[i][1] = p0.y * s[1]; f[i][2] = p0.z * s[2]; f[i][3] = p0.w * s[3];
    f[i][4] = p1.x * s[4]; f[i][5] = p1.y * s[5]; f[i][6] = p1.z * s[6]; f[i][7] = p1.w * s[7];
  }
#pragma unroll
  for (int j = 0; j < 8; ++j) {
    const float n = sqrtf(f[0][j] * f[0][j] + f[1][j] * f[1][j] + f[2][j] * f[2][j] + 1e-8f);
    const float g = 1.0f / ((1.0f + expf(-n)) * n);   // sigmoid(n)/n
    f[0][j] *= g; f[1][j] *= g; f[2][j] *= g;
  }
#pragma unroll
  for (int i = 0; i < 3; ++i) {
    s16x8 hi, lo;
#pragma unroll
    for (int j = 0; j < 8; ++j) {
      const unsigned short h = f2bf(f[i][j]);
      hi[j] = (short)h;
      lo[j] = (short)f2bf(f[i][j] - bf2f(h));
    }
    const size_t off = ablk(i * 1024 + b, v0);
    *(s16x8*)(ah + off) = hi;
    *(s16x8*)(al + off) = lo;
  }
}

// ---- direct-to-register bf16-pair MFMA GEMM + fused colsumsq, 3-deep --------
// One wave per block; wave owns a 64x64 tile (4x4 frags of 16x16x32).
// Fragments loaded global->VGPR (blocked layout IS fragment order). No LDS.
#define LOADF(A_, B_, t_)                                                      \
  {                                                                            \
    const size_t kb_ = (size_t)(t_) << 12;                                     \
    _Pragma("unroll")                                                          \
    for (int m_ = 0; m_ < 4; ++m_) {                                           \
      A_[m_]     = *(const s16x8*)(a_h + kb_ + (m_ << 10));                    \
      A_[4 + m_] = *(const s16x8*)(a_l + kb_ + (m_ << 10));                    \
      B_[m_]     = *(const s16x8*)(b_h + kb_ + (m_ << 10));                    \
      B_[4 + m_] = *(const s16x8*)(b_l + kb_ + (m_ << 10));                    \
    }                                                                          \
  }
#define COMPUTEF(A_, B_)                                                       \
  {                                                                            \
    _Pragma("unroll")                                                          \
    for (int m_ = 0; m_ < 4; ++m_)                                             \
      _Pragma("unroll")                                                        \
      for (int n_ = 0; n_ < 4; ++n_) {                                         \
        acc[m_][n_] = __builtin_amdgcn_mfma_f32_16x16x32_bf16(                 \
            A_[4 + m_], B_[n_], acc[m_][n_], 0, 0, 0);                         \
        acc[m_][n_] = __builtin_amdgcn_mfma_f32_16x16x32_bf16(                 \
            A_[m_], B_[4 + n_], acc[m_][n_], 0, 0, 0);                         \
        acc[m_][n_] = __builtin_amdgcn_mfma_f32_16x16x32_bf16(                 \
            A_[m_], B_[n_], acc[m_][n_], 0, 0, 0);                             \
      }                                                                        \
  }

__global__ __launch_bounds__(64, 1) void gemm_reg(
    const char* __restrict__ Ah, const char* __restrict__ Al,
    const char* __restrict__ Bh, const char* __restrict__ Bl,
    float* __restrict__ C, float* __restrict__ var) {
  const int bid = blockIdx.x;
  const int xcd = bid & 7, q = bid >> 3;          // q in 0..95
  const int tm = xcd * 6 + (q % 6);               // 0..47 (XCD M-stripe)
  const int tn = q / 6;                           // 0..15
  const int lane = threadIdx.x;
  const int rsel = lane & 15, kcsel = lane >> 4;

  // fragment base pointers: rowgroup m of the tile's 64-row block, step t:
  // base + (t<<12) + (m<<10) + lane*16  — 16B/lane, wave-contiguous 1KB.
  const size_t la = (size_t)lane << 4;
  const char* a_h = Ah + ((size_t)tm << 17) + la;
  const char* a_l = Al + ((size_t)tm << 17) + la;
  const char* b_h = Bh + ((size_t)tn << 17) + la;
  const char* b_l = Bl + ((size_t)tn << 17) + la;

  f32x4 acc[4][4] = {};
  s16x8 A0[8], B0[8], A1[8], B1[8], A2[8], B2[8];

  LOADF(A0, B0, 0);
  LOADF(A1, B1, 1);
  LOADF(A2, B2, 2);
  // steady state: compute t, t+1, t+2 while loading t+3, t+4, t+5.
  // 10 iters (t = 0,3,...,27) compute steps 0..29; guards skip load of t=32.
  for (int t = 0; t < 30; t += 3) {
    COMPUTEF(A0, B0);
    LOADF(A0, B0, t + 3);                    // t+3 <= 30 < 32 always
    COMPUTEF(A1, B1);
    LOADF(A1, B1, t + 4);                    // t+4 <= 31 < 32 always
    COMPUTEF(A2, B2);
    if (t + 5 < 32) LOADF(A2, B2, t + 5);    // skip only at t=27
  }
  COMPUTEF(A0, B0);              // step 30 (loaded at t=27)
  COMPUTEF(A1, B1);              // step 31 (loaded at t=27)

  // epilogue: linear C store + fused per-column sum of squares
  // frag (m,n) elem j: row = tm*64 + m*16 + kcsel*4 + j, col = tn*64 + n*16 + rsel
  const int r0 = tm * 64 + (kcsel << 2);
  const int c0 = tn * 64 + rsel;
  float csq[4] = {0.f, 0.f, 0.f, 0.f};
#pragma unroll
  for (int m = 0; m < 4; ++m)
#pragma unroll
    for (int n = 0; n < 4; ++n)
#pragma unroll
      for (int j = 0; j < 4; ++j) {
        const float v = acc[m][n][j];
        C[(size_t)(r0 + m * 16 + j) * 1024 + c0 + n * 16] = v;
        csq[n] += v * v;
      }
#pragma unroll
  for (int n = 0; n < 4; ++n) {
    csq[n] += __shfl_xor(csq[n], 16);
    csq[n] += __shfl_xor(csq[n], 32);
  }
  if (kcsel == 0) {
#pragma unroll
    for (int n = 0; n < 4; ++n)
      atomicAdd(&var[c0 + n * 16], csq[n]);
  }
}

// ---- final: out[b,i] = (1/32) * sum_v act[i][b][v] * wout[v] ----------------
__global__ void final_kernel(const char* __restrict__ ah, const char* __restrict__ al,
                             const float* __restrict__ wout, float* __restrict__ out) {
  const int b = blockIdx.x, tid = threadIdx.x;
  __shared__ float red[3][4];
  float s[3] = {0.f, 0.f, 0.f};
  if (tid < 128) {
    const int v0 = tid * 8;
#pragma unroll
    for (int i = 0; i < 3; ++i) {
      const size_t off = ablk(i * 1024 + b, v0);
      const s16x8 hi = *(const s16x8*)(ah + off);
      const s16x8 lo = *(const s16x8*)(al + off);
#pragma unroll
      for (int j = 0; j < 8; ++j)
        s[i] += (bf2f((unsigned short)hi[j]) + bf2f((unsigned short)lo[j])) * wout[v0 + j];
    }
  }
#pragma unroll
  for (int i = 0; i < 3; ++i)
    for (int o = 32; o >= 1; o >>= 1) s[i] += __shfl_down(s[i], o);
  if ((tid & 63) == 0)
#pragma unroll
    for (int i = 0; i < 3; ++i) red[i][tid >> 6] = s[i];
  __syncthreads();
  if (tid < 3) {
    const float t = red[tid][0] + red[tid][1] + red[tid][2] + red[tid][3];
    out[b * 3 + tid] = t * 0.03125f;
  }
}

extern "C" void kernel_launch(void* const* d_in, const int* in_sizes, int n_in,
                              void* d_out, int out_size, void* d_ws, size_t ws_size,
                              hipStream_t stream) {
  const float* x    = (const float*)d_in[0];
  const float* w1   = (const float*)d_in[1];
  const float* W    = (const float*)d_in[2];
  const float* bnw  = (const float*)d_in[3];
  const float* wout = (const float*)d_in[4];
  float* out = (float*)d_out;

  char* ws = (char*)d_ws;
  float*          var = (float*)ws;                         // 6*1024 f32 (32 KB resv)
  float*          pre = (float*)(ws + 32768);               // C buffer, 12 MB
  char*           ah  = ws + 12615680;                      // blocked bf16 (6 MB)
  char*           al  = ws + 18907136;                      // blocked bf16 (6 MB)
  unsigned short* wh  = (unsigned short*)(ws + 25198592);   // blocked bf16 (10 MB)
  unsigned short* wl  = (unsigned short*)(ws + 35684352);   // blocked bf16 (10 MB)

  hipMemsetAsync(var, 0, 6 * 1024 * sizeof(float), stream);
  convert_w<<<dim3(16, 16, 5), 256, 0, stream>>>(W, wh, wl);
  layer0_fused<<<dim3(4, 64), 256, 0, stream>>>(x, w1, pre, var);
  act_kernel<<<dim3(64, 8), 256, 0, stream>>>(pre, var, bnw, ah, al);
  for (int b = 0; b < 5; ++b) {
    gemm_reg<<<768, 64, 0, stream>>>(
        ah, al, (const char*)(wh + (size_t)b * PLANE), (const char*)(wl + (size_t)b * PLANE),
        pre, var + (b + 1) * 1024);
    act_kernel<<<dim3(64, 8), 256, 0, stream>>>(pre, var + (b + 1) * 1024,
                                                bnw + (size_t)(b + 1) * 4096, ah, al);
  }
  final_kernel<<<1024, 256, 0, stream>>>(ah, al, wout, out);
}

// Round 17
// 195.331 us; speedup vs baseline: 1.1864x; 1.1864x over previous
//
#include <hip/hip_runtime.h>
#include <hip/hip_bf16.h>
#include <cstdint>
#include <cstddef>

// ---------------------------------------------------------------------------
// E3nnMLPNorm: only the l=1 (d=3) irrep path is nonzero.
// layer0(+colsumsq) -> [gemm(+colsumsq) -> bn+gate] x5 -> final dot
// Precision: bf16 hi+lo pairs, 3 bf16 MFMA per fragment into f32 acc.
// R17: K-SPLIT x2 direct-to-register GEMM. R9..R16 all pinned at ~30us =
// 13 TB/s L2 traffic with <=1 wave/SIMD (768 waves fixed by 64x64 tiling).
// Now each C-tile = one 2-wave block: wave k computes K-half k in registers
// (16 steps, R15's loop), then LDS handoff + wave0 epilogue. Same bytes,
// same MFMA, 2x waves (1536 = 1.5/SIMD) -> partner wave covers vm stalls.
// ---------------------------------------------------------------------------

typedef short    s16x8 __attribute__((ext_vector_type(8)));
typedef float    f32x4 __attribute__((ext_vector_type(4)));

#define PLANE 1048576   // 1024*1024 elements per plane

__device__ __forceinline__ unsigned short f2bf(float f) {
  unsigned u = __builtin_bit_cast(unsigned, f);
  u += 0x7FFFu + ((u >> 16) & 1u);              // round-to-nearest-even
  return (unsigned short)(u >> 16);
}
__device__ __forceinline__ float bf2f(unsigned short h) {
  return __builtin_bit_cast(float, (unsigned)h << 16);
}

// byte offset of element (row, k) in the K-blocked bf16 operand layout:
// [row>>6][k>>5][(row>>4)&3][(k>>3)&3][row&15][k&7]
__device__ __forceinline__ size_t ablk(int row, int k) {
  return ((size_t)(row >> 6) << 17) + ((size_t)(k >> 5) << 12)
       + ((size_t)((row >> 4) & 3) << 10) + ((size_t)((k >> 3) & 3) << 8)
       + ((size_t)(row & 15) << 4) + ((size_t)(k & 7) << 1);
}

// ---- W[b,0] (f32 [u][v]) -> blocked bf16 hi/lo (row=v, k=u), 1/32 folded ----
__global__ void convert_w(const float* __restrict__ W,
                          unsigned short* __restrict__ Wh,
                          unsigned short* __restrict__ Wl) {
  __shared__ float t[64][65];
  const int u0 = blockIdx.x * 64, v0 = blockIdx.y * 64;
  const float* Wb = W + (size_t)blockIdx.z * 4194304;   // [5][4][1024][1024], irrep 0
  char* Whb = (char*)(Wh + (size_t)blockIdx.z * PLANE);
  char* Wlb = (char*)(Wl + (size_t)blockIdx.z * PLANE);
  const int c = threadIdx.x & 63, r4 = threadIdx.x >> 6;
#pragma unroll
  for (int i = 0; i < 16; ++i) {
    const int r = i * 4 + r4;
    t[r][c] = Wb[(size_t)(u0 + r) * 1024 + v0 + c];
  }
  __syncthreads();
#pragma unroll
  for (int i = 0; i < 16; ++i) {
    const int r = i * 4 + r4;   // local v index
    const float w = t[c][r] * 0.03125f;      // exact pow2 scale
    const unsigned short hi = f2bf(w);
    const size_t off = ablk(v0 + r, u0 + c);
    *(unsigned short*)(Whb + off) = hi;
    *(unsigned short*)(Wlb + off) = f2bf(w - bf2f(hi));
  }
}

// ---- layer0 + fused colsumsq: pre[i][b][v] (linear f32), var[v] += sum f^2 --
__global__ void layer0_fused(const float* __restrict__ x, const float* __restrict__ w1,
                             float* __restrict__ pre, float* __restrict__ var) {
  const int v = blockIdx.x * 256 + threadIdx.x;
  const int b0 = blockIdx.y * 16;
  const float a0 = w1[v], a1 = w1[1024 + v];
  const float inv = 0.70710678118654752f;
  float ssq = 0.f;
#pragma unroll 4
  for (int bb = 0; bb < 16; ++bb) {
    const int b = b0 + bb;
    const float* xb = x + b * 6;                    // x flat [B][2][3]
#pragma unroll
    for (int i = 0; i < 3; ++i) {
      const float f = (xb[i] * a0 + xb[3 + i] * a1) * inv;
      pre[(size_t)i * PLANE + (size_t)b * 1024 + v] = f;
      ssq += f * f;
    }
  }
  atomicAdd(&var[v], ssq);
}

// ---- batchnorm + norm-gated sigmoid: pre (linear f32) -> blocked bf16 hi/lo -
// block: 16 b x 128 v; thread: b = 16bx + (tid&15), v0 = 128by + (tid>>4)*8.
__global__ void act_kernel(const float* __restrict__ pre, const float* __restrict__ var,
                           const float* __restrict__ bnw,
                           char* __restrict__ ah, char* __restrict__ al) {
  const int tid = threadIdx.x;
  const int b  = blockIdx.x * 16 + (tid & 15);
  const int v0 = blockIdx.y * 128 + (tid >> 4) * 8;
  float s[8];
#pragma unroll
  for (int j = 0; j < 8; ++j)
    s[j] = bnw[v0 + j] / sqrtf(var[v0 + j] * (1.0f / 3072.0f) + 1e-5f);
  float f[3][8];
#pragma unroll
  for (int i = 0; i < 3; ++i) {
    const float4 p0 = *(const float4*)&pre[(size_t)i * PLANE + (size_t)b * 1024 + v0];
    const float4 p1 = *(const float4*)&pre[(size_t)i * PLANE + (size_t)b * 1024 + v0 + 4];
    f[i][0] = p0.x * s[0]; f[i][1] = p0.y * s[1]; f[i][2] = p0.z * s[2]; f[i][3] = p0.w * s[3];
    f[i][4] = p1.x * s[4]; f[i][5] = p1.y * s[5]; f[i][6] = p1.z * s[6]; f[i][7] = p1.w * s[7];
  }
#pragma unroll
  for (int j = 0; j < 8; ++j) {
    const float n = sqrtf(f[0][j] * f[0][j] + f[1][j] * f[1][j] + f[2][j] * f[2][j] + 1e-8f);
    const float g = 1.0f / ((1.0f + expf(-n)) * n);   // sigmoid(n)/n
    f[0][j] *= g; f[1][j] *= g; f[2][j] *= g;
  }
#pragma unroll
  for (int i = 0; i < 3; ++i) {
    s16x8 hi, lo;
#pragma unroll
    for (int j = 0; j < 8; ++j) {
      const unsigned short h = f2bf(f[i][j]);
      hi[j] = (short)h;
      lo[j] = (short)f2bf(f[i][j] - bf2f(h));
    }
    const size_t off = ablk(i * 1024 + b, v0);
    *(s16x8*)(ah + off) = hi;
    *(s16x8*)(al + off) = lo;
  }
}

// ---- K-split x2 direct-to-register bf16-pair MFMA GEMM + fused colsumsq -----
// 2 waves per block; wave k owns K in [512k, 512k+512) of the block's 64x64
// tile (4x4 frags). Fragments loaded global->VGPR. LDS only for the final
// cross-wave accumulator handoff (16 KB).
#define LOADF(A_, B_, t_)                                                      \
  {                                                                            \
    const size_t kb_ = (size_t)(t_) << 12;                                     \
    _Pragma("unroll")                                                          \
    for (int m_ = 0; m_ < 4; ++m_) {                                           \
      A_[m_]     = *(const s16x8*)(a_h + kb_ + (m_ << 10));                    \
      A_[4 + m_] = *(const s16x8*)(a_l + kb_ + (m_ << 10));                    \
      B_[m_]     = *(const s16x8*)(b_h + kb_ + (m_ << 10));                    \
      B_[4 + m_] = *(const s16x8*)(b_l + kb_ + (m_ << 10));                    \
    }                                                                          \
  }
#define COMPUTEF(A_, B_)                                                       \
  {                                                                            \
    _Pragma("unroll")                                                          \
    for (int m_ = 0; m_ < 4; ++m_)                                             \
      _Pragma("unroll")                                                        \
      for (int n_ = 0; n_ < 4; ++n_) {                                         \
        acc[m_][n_] = __builtin_amdgcn_mfma_f32_16x16x32_bf16(                 \
            A_[4 + m_], B_[n_], acc[m_][n_], 0, 0, 0);                         \
        acc[m_][n_] = __builtin_amdgcn_mfma_f32_16x16x32_bf16(                 \
            A_[m_], B_[4 + n_], acc[m_][n_], 0, 0, 0);                         \
        acc[m_][n_] = __builtin_amdgcn_mfma_f32_16x16x32_bf16(                 \
            A_[m_], B_[n_], acc[m_][n_], 0, 0, 0);                             \
      }                                                                        \
  }

__global__ __launch_bounds__(128, 2) void gemm_reg(
    const char* __restrict__ Ah, const char* __restrict__ Al,
    const char* __restrict__ Bh, const char* __restrict__ Bl,
    float* __restrict__ C, float* __restrict__ var) {
  __shared__ float red[4096];                     // 16 KB cross-wave handoff
  const int bid = blockIdx.x;
  const int xcd = bid & 7, q = bid >> 3;          // q in 0..95
  const int tm = xcd * 6 + (q % 6);               // 0..47 (XCD M-stripe)
  const int tn = q / 6;                           // 0..15
  const int lane = threadIdx.x & 63;
  const int wave = threadIdx.x >> 6;              // K-half owner: 0 or 1
  const int rsel = lane & 15, kcsel = lane >> 4;

  // fragment base pointers: + wave's K-half (16 K-steps x 4KB = 64KB = <<16)
  const size_t la = ((size_t)lane << 4) + ((size_t)wave << 16);
  const char* a_h = Ah + ((size_t)tm << 17) + la;
  const char* a_l = Al + ((size_t)tm << 17) + la;
  const char* b_h = Bh + ((size_t)tn << 17) + la;
  const char* b_l = Bl + ((size_t)tn << 17) + la;

  f32x4 acc[4][4] = {};
  s16x8 A0[8], B0[8], A1[8], B1[8];

  LOADF(A0, B0, 0);
  LOADF(A1, B1, 1);
  for (int t = 0; t < 14; t += 2) {
    COMPUTEF(A0, B0);            // step t
    LOADF(A0, B0, t + 2);
    COMPUTEF(A1, B1);            // step t+1
    LOADF(A1, B1, t + 3);        // last iter loads step 15
  }
  COMPUTEF(A0, B0);              // step 14
  COMPUTEF(A1, B1);              // step 15

  // cross-wave combine: wave1 -> LDS -> wave0
  if (wave == 1) {
#pragma unroll
    for (int m = 0; m < 4; ++m)
#pragma unroll
      for (int n = 0; n < 4; ++n)
#pragma unroll
        for (int j = 0; j < 4; ++j)
          red[(((((m << 2) | n) << 2) | j) << 6) | lane] = acc[m][n][j];
  }
  __syncthreads();
  if (wave == 0) {
    // epilogue: linear C store + fused per-column sum of squares
    // frag (m,n) elem j: row = tm*64 + m*16 + kcsel*4 + j, col = tn*64 + n*16 + rsel
    const int r0 = tm * 64 + (kcsel << 2);
    const int c0 = tn * 64 + rsel;
    float csq[4] = {0.f, 0.f, 0.f, 0.f};
#pragma unroll
    for (int m = 0; m < 4; ++m)
#pragma unroll
      for (int n = 0; n < 4; ++n)
#pragma unroll
        for (int j = 0; j < 4; ++j) {
          const float v = acc[m][n][j] + red[(((((m << 2) | n) << 2) | j) << 6) | lane];
          C[(size_t)(r0 + m * 16 + j) * 1024 + c0 + n * 16] = v;
          csq[n] += v * v;
        }
#pragma unroll
    for (int n = 0; n < 4; ++n) {
      csq[n] += __shfl_xor(csq[n], 16);
      csq[n] += __shfl_xor(csq[n], 32);
    }
    if (kcsel == 0) {
#pragma unroll
      for (int n = 0; n < 4; ++n)
        atomicAdd(&var[c0 + n * 16], csq[n]);
    }
  }
}

// ---- final: out[b,i] = (1/32) * sum_v act[i][b][v] * wout[v] ----------------
__global__ void final_kernel(const char* __restrict__ ah, const char* __restrict__ al,
                             const float* __restrict__ wout, float* __restrict__ out) {
  const int b = blockIdx.x, tid = threadIdx.x;
  __shared__ float red[3][4];
  float s[3] = {0.f, 0.f, 0.f};
  if (tid < 128) {
    const int v0 = tid * 8;
#pragma unroll
    for (int i = 0; i < 3; ++i) {
      const size_t off = ablk(i * 1024 + b, v0);
      const s16x8 hi = *(const s16x8*)(ah + off);
      const s16x8 lo = *(const s16x8*)(al + off);
#pragma unroll
      for (int j = 0; j < 8; ++j)
        s[i] += (bf2f((unsigned short)hi[j]) + bf2f((unsigned short)lo[j])) * wout[v0 + j];
    }
  }
#pragma unroll
  for (int i = 0; i < 3; ++i)
    for (int o = 32; o >= 1; o >>= 1) s[i] += __shfl_down(s[i], o);
  if ((tid & 63) == 0)
#pragma unroll
    for (int i = 0; i < 3; ++i) red[i][tid >> 6] = s[i];
  __syncthreads();
  if (tid < 3) {
    const float t = red[tid][0] + red[tid][1] + red[tid][2] + red[tid][3];
    out[b * 3 + tid] = t * 0.03125f;
  }
}

extern "C" void kernel_launch(void* const* d_in, const int* in_sizes, int n_in,
                              void* d_out, int out_size, void* d_ws, size_t ws_size,
                              hipStream_t stream) {
  const float* x    = (const float*)d_in[0];
  const float* w1   = (const float*)d_in[1];
  const float* W    = (const float*)d_in[2];
  const float* bnw  = (const float*)d_in[3];
  const float* wout = (const float*)d_in[4];
  float* out = (float*)d_out;

  char* ws = (char*)d_ws;
  float*          var = (float*)ws;                         // 6*1024 f32 (32 KB resv)
  float*          pre = (float*)(ws + 32768);               // C buffer, 12 MB
  char*           ah  = ws + 12615680;                      // blocked bf16 (6 MB)
  char*           al  = ws + 18907136;                      // blocked bf16 (6 MB)
  unsigned short* wh  = (unsigned short*)(ws + 25198592);   // blocked bf16 (10 MB)
  unsigned short* wl  = (unsigned short*)(ws + 35684352);   // blocked bf16 (10 MB)

  hipMemsetAsync(var, 0, 6 * 1024 * sizeof(float), stream);
  convert_w<<<dim3(16, 16, 5), 256, 0, stream>>>(W, wh, wl);
  layer0_fused<<<dim3(4, 64), 256, 0, stream>>>(x, w1, pre, var);
  act_kernel<<<dim3(64, 8), 256, 0, stream>>>(pre, var, bnw, ah, al);
  for (int b = 0; b < 5; ++b) {
    gemm_reg<<<768, 128, 0, stream>>>(
        ah, al, (const char*)(wh + (size_t)b * PLANE), (const char*)(wl + (size_t)b * PLANE),
        pre, var + (b + 1) * 1024);
    act_kernel<<<dim3(64, 8), 256, 0, stream>>>(pre, var + (b + 1) * 1024,
                                                bnw + (size_t)(b + 1) * 4096, ah, al);
  }
  final_kernel<<<1024, 256, 0, stream>>>(ah, al, wout, out);
}